// Round 3
// baseline (565.944 us; speedup 1.0000x reference)
//
#include <hip/hip_runtime.h>

typedef __attribute__((ext_vector_type(8))) short short8;
typedef __attribute__((ext_vector_type(4))) float f32x4;

#define B_ 64
#define H_ 24
#define N_ 32
#define F_ 256

__device__ __forceinline__ float bf2f(unsigned short u) {
    return __uint_as_float(((unsigned)u) << 16);
}
__device__ __forceinline__ unsigned short f2bf(float f) {
    unsigned u = __float_as_uint(f);
    u += 0x7fffu + ((u >> 16) & 1u);   // RNE
    return (unsigned short)(u >> 16);
}
// pack truncated-bf16(f0) into low16, truncated-bf16(f1) into high16
__device__ __forceinline__ unsigned pack_hi(float f0, float f1) {
    return (__float_as_uint(f0) >> 16) | (__float_as_uint(f1) & 0xffff0000u);
}
// residual after truncated-bf16: exact in fp32
__device__ __forceinline__ float res_lo(float f) {
    return f - __uint_as_float(__float_as_uint(f) & 0xffff0000u);
}

struct StageT {
    unsigned short Ah[64 * 32];   // 4 KB
    unsigned short Al[64 * 32];   // 4 KB
    unsigned short Wh[256 * 32];  // 16 KB
    unsigned short Wl[256 * 32];  // 16 KB
};
union Smem {
    StageT t;                     // 40 KB exactly -> 4 blocks/CU
    unsigned short outT[64 * 256];// 32 KB (V epilogue; also aliases slog)
};

// C[b][g] = sum_f A[b][f]*W[f][g]  (64 x 256 x 256 over ks in [ksBeg,ksEnd)).
// bf16 MFMA; SPLIT adds hi*lo + lo*hi passes (3xTF32-style).
//
// True 2-phase pipeline (guide T3/T4): RAW s_barrier with lgkmcnt(0) only --
// the compiler's __syncthreads() vmcnt(0) drain is what killed r2's overlap.
// Tile k+1's global loads are issued at the TOP of iteration k; their
// register-precise vmcnt waits land at iteration k+1's pack, so HBM latency
// hides under pack + barrier + ds_read + MFMA (the full iteration).
// Prefetch goes to registers only => no LDS hazard across raw barriers;
// LDS write->read visibility needs only lgkmcnt(0)+barrier (single buffer:
// write-after-read is protected by the lgkm-drained barrier at loop top).
template<bool SPLIT>
__device__ __forceinline__ void gemm_f32(
    const float* __restrict__ Ab, long rstride,
    const float* __restrict__ Wb, Smem& sm, f32x4 acc[4][4],
    int ksBeg, int ksEnd)
{
    const int t    = threadIdx.x;
    const int lane = t & 63;
    const int wv   = t >> 6;
    const int l15  = lane & 15;
    const int quad = lane >> 4;
    const int arow = t >> 2, achk = (t & 3) * 8;
    const float* aSrc = Ab + (long)arow * rstride + achk;
    const float* wSrc = Wb + (long)(wv * 8) * 256 + lane * 4;
    const int pos  = wv ^ (lane & 3);        // xor-swizzled 16B chunk (stage)
    const int bpos = quad ^ ((l15 >> 2) & 3);// matching swizzle (frag read)

    union F4 { float4 v; float e[4]; };

    // ---- prologue: load first tile into registers ----
    float4 a0 = *(const float4*)(aSrc + ksBeg * 32);
    float4 a1 = *(const float4*)(aSrc + ksBeg * 32 + 4);
    F4 r[8];
    #pragma unroll
    for (int i = 0; i < 8; i++)
        r[i].v = *(const float4*)(wSrc + (long)(ksBeg * 32 + i) * 256);

    for (int ks = ksBeg; ks < ksEnd; ks++) {
        // barrier A: all waves' prior frag reads complete (lgkm only; any
        // prefetched global loads stay in flight across the barrier)
        asm volatile("s_waitcnt lgkmcnt(0)" ::: "memory");
        __builtin_amdgcn_s_barrier();

        // ---- issue NEXT tile's loads first: maximal overlap window ----
        float4 na0, na1;
        F4 nr[8];
        if (ks + 1 < ksEnd) {
            const int k1 = (ks + 1) * 32;
            na0 = *(const float4*)(aSrc + k1);
            na1 = *(const float4*)(aSrc + k1 + 4);
            #pragma unroll
            for (int i = 0; i < 8; i++)
                nr[i].v = *(const float4*)(wSrc + (long)(k1 + i) * 256);
        }

        // ---- pack current registers -> LDS (precise vmcnt waits here) ----
        {
            uint4 h;
            h.x = pack_hi(a0.x, a0.y); h.y = pack_hi(a0.z, a0.w);
            h.z = pack_hi(a1.x, a1.y); h.w = pack_hi(a1.z, a1.w);
            *(uint4*)&sm.t.Ah[arow * 32 + achk] = h;
            if (SPLIT) {
                uint4 l;
                l.x = pack_hi(res_lo(a0.x), res_lo(a0.y));
                l.y = pack_hi(res_lo(a0.z), res_lo(a0.w));
                l.z = pack_hi(res_lo(a1.x), res_lo(a1.y));
                l.w = pack_hi(res_lo(a1.z), res_lo(a1.w));
                *(uint4*)&sm.t.Al[arow * 32 + achk] = l;
            }
            #pragma unroll
            for (int j = 0; j < 4; j++) {
                uint4 hh;
                hh.x = pack_hi(r[0].e[j], r[1].e[j]);
                hh.y = pack_hi(r[2].e[j], r[3].e[j]);
                hh.z = pack_hi(r[4].e[j], r[5].e[j]);
                hh.w = pack_hi(r[6].e[j], r[7].e[j]);
                *(uint4*)&sm.t.Wh[(lane * 4 + j) * 32 + pos * 8] = hh;
                if (SPLIT) {
                    uint4 ll;
                    ll.x = pack_hi(res_lo(r[0].e[j]), res_lo(r[1].e[j]));
                    ll.y = pack_hi(res_lo(r[2].e[j]), res_lo(r[3].e[j]));
                    ll.z = pack_hi(res_lo(r[4].e[j]), res_lo(r[5].e[j]));
                    ll.w = pack_hi(res_lo(r[6].e[j]), res_lo(r[7].e[j]));
                    *(uint4*)&sm.t.Wl[(lane * 4 + j) * 32 + pos * 8] = ll;
                }
            }
        }
        // barrier B: staged tile visible (lgkm only; prefetch stays in flight)
        asm volatile("s_waitcnt lgkmcnt(0)" ::: "memory");
        __builtin_amdgcn_s_barrier();

        // ---- fragments + MFMA ----
        {
            short8 ah[4];
            #pragma unroll
            for (int mi = 0; mi < 4; mi++)
                ah[mi] = *(const short8*)&sm.t.Ah[(mi * 16 + l15) * 32 + quad * 8];
            if (SPLIT) {
                short8 al[4];
                #pragma unroll
                for (int mi = 0; mi < 4; mi++)
                    al[mi] = *(const short8*)&sm.t.Al[(mi * 16 + l15) * 32 + quad * 8];
                #pragma unroll
                for (int ni = 0; ni < 4; ni++) {
                    int g = wv * 64 + ni * 16 + l15;
                    short8 bh = *(const short8*)&sm.t.Wh[g * 32 + bpos * 8];
                    short8 bl = *(const short8*)&sm.t.Wl[g * 32 + bpos * 8];
                    #pragma unroll
                    for (int mi = 0; mi < 4; mi++) {
                        acc[mi][ni] = __builtin_amdgcn_mfma_f32_16x16x32_bf16(al[mi], bh, acc[mi][ni], 0, 0, 0);
                        acc[mi][ni] = __builtin_amdgcn_mfma_f32_16x16x32_bf16(ah[mi], bl, acc[mi][ni], 0, 0, 0);
                        acc[mi][ni] = __builtin_amdgcn_mfma_f32_16x16x32_bf16(ah[mi], bh, acc[mi][ni], 0, 0, 0);
                    }
                }
            } else {
                #pragma unroll
                for (int ni = 0; ni < 4; ni++) {
                    int g = wv * 64 + ni * 16 + l15;
                    short8 bh = *(const short8*)&sm.t.Wh[g * 32 + bpos * 8];
                    #pragma unroll
                    for (int mi = 0; mi < 4; mi++)
                        acc[mi][ni] = __builtin_amdgcn_mfma_f32_16x16x32_bf16(ah[mi], bh, acc[mi][ni], 0, 0, 0);
                }
            }
        }
        // ---- rotate prefetched registers ----
        a0 = na0; a1 = na1;
        #pragma unroll
        for (int i = 0; i < 8; i++) r[i] = nr[i];
    }
}

// Kernel 0: zero qws (2 MB) for the atomic K-split accumulation
__global__ __launch_bounds__(256) void k_zero(float4* __restrict__ p) {
    p[blockIdx.x * 256 + threadIdx.x] = (float4){0.f, 0.f, 0.f, 0.f};
}

// Kernel 1: qws[n][b][g] += partial(Q[b,n,:] @ Wq[n]) + bq (y==0 adds bias)
// grid (N, 8): blockIdx.y = one K-step each -> 256 blocks, no serial K chain.
__global__ __launch_bounds__(256, 4) void k_qproj(
    const float* __restrict__ Q, const float* __restrict__ Wq,
    const float* __restrict__ bq, float* __restrict__ qws)
{
    const int n  = blockIdx.x;
    const int ks = blockIdx.y;
    __shared__ Smem sm;
    f32x4 acc[4][4];
    #pragma unroll
    for (int i = 0; i < 4; i++)
        #pragma unroll
        for (int j = 0; j < 4; j++) acc[i][j] = (f32x4){0.f, 0.f, 0.f, 0.f};

    gemm_f32<true>(Q + n * F_, (long)(N_ * F_), Wq + (long)n * F_ * F_, sm, acc,
                   ks, ks + 1);

    const int t = threadIdx.x, lane = t & 63, wv = t >> 6;
    const int l15 = lane & 15, quad = lane >> 4;
    const float* bias = bq + n * F_;
    float* dst = qws + (long)n * (B_ * F_);
    #pragma unroll
    for (int ni = 0; ni < 4; ni++) {
        int g = wv * 64 + ni * 16 + l15;
        float bb = (ks == 0) ? bias[g] : 0.f;
        #pragma unroll
        for (int mi = 0; mi < 4; mi++)
            #pragma unroll
            for (int reg = 0; reg < 4; reg++) {
                int r = mi * 16 + quad * 4 + reg;
                atomicAdd(&dst[r * 256 + g], acc[mi][ni][reg] + bb);
            }
    }
}

// Kernel 2: grid (N*H, 2). y==0: KWk (split) + fused logits. y==1: VWv -> vws bf16.
__global__ __launch_bounds__(256, 4) void k_kvproj(
    const float* __restrict__ Kx, const float* __restrict__ Vx,
    const float* __restrict__ Wk, const float* __restrict__ bk,
    const float* __restrict__ Wv, const float* __restrict__ bv,
    const float* __restrict__ qws, float* __restrict__ logits,
    unsigned short* __restrict__ vws)
{
    const int nh = blockIdx.x;
    const int n = nh / H_;
    const int h = nh - n * H_;
    const bool isV = (blockIdx.y != 0);
    const float* X    = isV ? Vx : Kx;
    const float* W    = (isV ? Wv : Wk) + (long)nh * F_ * F_;
    const float* bias = (isV ? bv : bk) + nh * F_;

    __shared__ Smem sm;           // 40960 B exactly; slog aliases sm
    const int t = threadIdx.x;

    f32x4 acc[4][4];
    #pragma unroll
    for (int i = 0; i < 4; i++)
        #pragma unroll
        for (int j = 0; j < 4; j++) acc[i][j] = (f32x4){0.f, 0.f, 0.f, 0.f};

    const float* Xb = X + (long)(h * N_ + n) * F_;
    if (isV) gemm_f32<false>(Xb, (long)(H_ * N_ * F_), W, sm, acc, 0, 8);
    else     gemm_f32<true >(Xb, (long)(H_ * N_ * F_), W, sm, acc, 0, 8);

    const int lane = t & 63, wv = t >> 6, l15 = lane & 15, quad = lane >> 4;

    if (!isV) {
        // slog aliases the staging LDS: zero it only after all frag reads done
        float* slog = (float*)&sm;
        __syncthreads();
        if (t < 64) slog[t] = 0.f;
        __syncthreads();
        // logits[b] = sum_g qws[n,b,g] * (KWk[b,g] + bk[g])
        const float* qrow = qws + (long)n * (B_ * F_);
        #pragma unroll
        for (int mi = 0; mi < 4; mi++) {
            float p[4] = {0.f, 0.f, 0.f, 0.f};
            #pragma unroll
            for (int ni = 0; ni < 4; ni++) {
                int g = wv * 64 + ni * 16 + l15;
                float bb = bias[g];
                #pragma unroll
                for (int reg = 0; reg < 4; reg++) {
                    int r = mi * 16 + quad * 4 + reg;
                    p[reg] += (acc[mi][ni][reg] + bb) * qrow[r * 256 + g];
                }
            }
            #pragma unroll
            for (int off = 1; off < 16; off <<= 1)
                #pragma unroll
                for (int reg = 0; reg < 4; reg++)
                    p[reg] += __shfl_xor(p[reg], off, 64);
            if (l15 == 0)
                #pragma unroll
                for (int reg = 0; reg < 4; reg++)
                    atomicAdd(&slog[mi * 16 + quad * 4 + reg], p[reg]);
        }
        __syncthreads();
        if (t < 64) logits[(long)nh * 64 + t] = slog[t];
    } else {
        __syncthreads();   // frag reads done before overwriting smem
        #pragma unroll
        for (int ni = 0; ni < 4; ni++) {
            int g = wv * 64 + ni * 16 + l15;
            float bb = bias[g];
            #pragma unroll
            for (int mi = 0; mi < 4; mi++)
                #pragma unroll
                for (int reg = 0; reg < 4; reg++) {
                    int r = mi * 16 + quad * 4 + reg;
                    sm.outT[r * 256 + g] = f2bf(acc[mi][ni][reg] + bb);
                }
        }
        __syncthreads();
        unsigned short* dst = vws + (long)nh * (B_ * F_);
        #pragma unroll
        for (int it = 0; it < 8; it++) {
            int row = it * 8 + (t >> 5);
            int c = t & 31;
            uint4 v = *(const uint4*)(&sm.outT[row * 256 + c * 8]);
            *(uint4*)(dst + row * 256 + c * 8) = v;
        }
    }
}

// Kernel 3: per (b,n): softmax over H, write scores, combine VWv -> heads
__global__ __launch_bounds__(64) void k_attn(
    const float* __restrict__ logits,
    const unsigned short* __restrict__ vws,
    float* __restrict__ out)
{
    const int bx = blockIdx.x;
    const int b = bx >> 5;      // B=64
    const int n = bx & 31;      // N=32
    const int t = threadIdx.x;
    __shared__ float sl[24], se[24];
    if (t < 24) sl[t] = logits[(long)(n * H_ + t) * 64 + b];
    __syncthreads();
    float mx = -1e30f;
    #pragma unroll
    for (int h = 0; h < H_; h++) mx = fmaxf(mx, sl[h]);
    if (t < 24) se[t] = expf(sl[t] - mx);
    __syncthreads();
    float den = 0.f;
    #pragma unroll
    for (int h = 0; h < H_; h++) den += se[h];
    float inv = 1.0f / den;
    if (t < 24)
        out[(long)B_ * N_ * F_ + (long)(b * N_ + n) * H_ + t] = se[t] * inv;

    const int g0 = t * 4;
    float hv[4] = {0.f, 0.f, 0.f, 0.f};
    #pragma unroll
    for (int h = 0; h < H_; h++) {
        float s = se[h] * inv;
        const unsigned short* vp = vws + (((long)(n * H_ + h) * 64 + b) << 8) + g0;
        union { uint2 u; unsigned short e[4]; } vv;
        vv.u = *(const uint2*)vp;
        #pragma unroll
        for (int j = 0; j < 4; j++) hv[j] += s * bf2f(vv.e[j]);
    }
    float4 ov = make_float4(hv[0], hv[1], hv[2], hv[3]);
    *(float4*)(out + ((long)b * N_ + n) * F_ + g0) = ov;
}

extern "C" void kernel_launch(void* const* d_in, const int* in_sizes, int n_in,
                              void* d_out, int out_size, void* d_ws, size_t ws_size,
                              hipStream_t stream) {
    const float* Q  = (const float*)d_in[0];
    const float* K  = (const float*)d_in[1];
    const float* V  = (const float*)d_in[2];
    const float* Wq = (const float*)d_in[3];
    const float* bq = (const float*)d_in[4];
    const float* Wk = (const float*)d_in[5];
    const float* bk = (const float*)d_in[6];
    const float* Wv = (const float*)d_in[7];
    const float* bv = (const float*)d_in[8];

    char* ws = (char*)d_ws;
    float* qws          = (float*)ws;                               // N*B*F fp32 = 2 MB
    float* logits       = (float*)(ws + 2097152);                   // N*H*B fp32 = 192 KB
    unsigned short* vws = (unsigned short*)(ws + 2097152 + 262144); // N*H*B*F bf16 = 24 MB

    k_zero<<<512, 256, 0, stream>>>((float4*)qws);
    k_qproj<<<dim3(N_, 8), 256, 0, stream>>>(Q, Wq, bq, qws);
    k_kvproj<<<dim3(N_ * H_, 2), 256, 0, stream>>>(K, V, Wk, bk, Wv, bv, qws, logits, vws);
    k_attn<<<B_ * N_, 64, 0, stream>>>(logits, vws, (float*)d_out);
}

// Round 4
// 486.671 us; speedup vs baseline: 1.1629x; 1.1629x over previous
//
#include <hip/hip_runtime.h>

typedef __attribute__((ext_vector_type(8))) short short8;
typedef __attribute__((ext_vector_type(4))) float f32x4;

#define B_ 64
#define H_ 24
#define N_ 32
#define F_ 256

__device__ __forceinline__ float bf2f(unsigned short u) {
    return __uint_as_float(((unsigned)u) << 16);
}
__device__ __forceinline__ unsigned short f2bf(float f) {
    unsigned u = __float_as_uint(f);
    u += 0x7fffu + ((u >> 16) & 1u);   // RNE
    return (unsigned short)(u >> 16);
}
// pack truncated-bf16(f0) into low16, truncated-bf16(f1) into high16
__device__ __forceinline__ unsigned pack_hi(float f0, float f1) {
    return (__float_as_uint(f0) >> 16) | (__float_as_uint(f1) & 0xffff0000u);
}
// residual after truncated-bf16: exact in fp32
__device__ __forceinline__ float res_lo(float f) {
    return f - __uint_as_float(__float_as_uint(f) & 0xffff0000u);
}

union U4S8 { uint4 u; short8 s; };

// async global->LDS, 16B per lane (wave-uniform LDS base + lane*16)
__device__ __forceinline__ void gload16(const float* g, float* l) {
    __builtin_amdgcn_global_load_lds(
        (const __attribute__((address_space(1))) void*)g,
        (__attribute__((address_space(3))) void*)l, 16, 0, 0);
}

struct StageBufs {
    float A[2][64 * 32];    // 2 x 8 KB  fp32 A tile (64 rows x 32 k)
    float W[2][32 * 256];   // 2 x 32 KB fp32 W tile (32 k x 256 g)
};
union Smem {
    StageBufs s;                   // 80 KB -> 2 blocks/CU
    unsigned short outT[64 * 256]; // 32 KB (V epilogue)
    float slog[64];                // K epilogue logits accum
};

// C[b][g] = sum_f A[b][f]*W[f][g]  (64 x 256 x 256), bf16 MFMA.
// SPLIT adds hi*lo + lo*hi passes (3xTF32-style) for fp32-grade accuracy.
//
// T3 minimum-2-phase with global_load_lds: tiles staged as RAW FP32 via
// async DMA (no VGPR round-trip => no spill pressure, r3's failure mode).
// Double-buffered LDS; counted s_waitcnt vmcnt(10) (next tile's 10 DMAs
// stay in flight across barriers -- never drained to 0 in the main loop).
// bf16 packing happens at fragment-read time from fp32 LDS: bit-identical
// values and accumulation order to the original staged version.
template<bool SPLIT>
__device__ __forceinline__ void gemm_f32(
    const float* __restrict__ Ab, long rstride,
    const float* __restrict__ Wb, Smem& sm, f32x4 acc[4][4])
{
    const int t    = threadIdx.x;
    const int lane = t & 63;
    const int wv   = t >> 6;
    const int l15  = lane & 15;
    const int quad = lane >> 4;

    // staging geometry: per tile, per wave: 2 A-DMAs + 8 W-DMAs (1 KB each)
    const int aseg0 = wv * 2;                 // A 8-row segment index
    const int arow0 = aseg0 * 8 + (lane >> 3);
    const int acol  = (lane & 7) * 4;

    auto STAGE = [&](int ks, int b) {
        const int k0 = ks * 32;
        #pragma unroll
        for (int i = 0; i < 2; i++) {
            const float* src = Ab + (long)(arow0 + i * 8) * rstride + k0 + acol;
            gload16(src, &sm.s.A[b][(aseg0 + i) * 256]);
        }
        #pragma unroll
        for (int j = 0; j < 8; j++) {
            const int k = wv * 8 + j;
            const float* src = Wb + (long)(k0 + k) * 256 + lane * 4;
            gload16(src, &sm.s.W[b][k * 256]);
        }
    };

    STAGE(0, 0);
    #pragma unroll
    for (int ks = 0; ks < 8; ks++) {
        const int cur = ks & 1;
        // barrier 1: all waves done reading buf[cur^1] (prev compute)
        asm volatile("s_waitcnt lgkmcnt(0)" ::: "memory");
        __builtin_amdgcn_s_barrier();
        asm volatile("" ::: "memory");
        if (ks < 7) {
            STAGE(ks + 1, cur ^ 1);
            asm volatile("s_waitcnt vmcnt(10)" ::: "memory"); // tile cur done; next 10 in flight
        } else {
            asm volatile("s_waitcnt vmcnt(0)" ::: "memory");  // last tile
        }
        // barrier 2: tile cur staged by all waves
        __builtin_amdgcn_s_barrier();
        asm volatile("" ::: "memory");

        const float* Af = sm.s.A[cur];
        const float* Wf = sm.s.W[cur];

        // ---- A fragments: fp32 -> bf16 hi/lo in registers ----
        short8 ah[4], al[4];
        #pragma unroll
        for (int mi = 0; mi < 4; mi++) {
            const float* ap = Af + (mi * 16 + l15) * 32 + quad * 8;
            float4 a0 = *(const float4*)ap;
            float4 a1 = *(const float4*)(ap + 4);
            U4S8 h;
            h.u.x = pack_hi(a0.x, a0.y); h.u.y = pack_hi(a0.z, a0.w);
            h.u.z = pack_hi(a1.x, a1.y); h.u.w = pack_hi(a1.z, a1.w);
            ah[mi] = h.s;
            if (SPLIT) {
                U4S8 l;
                l.u.x = pack_hi(res_lo(a0.x), res_lo(a0.y));
                l.u.y = pack_hi(res_lo(a0.z), res_lo(a0.w));
                l.u.z = pack_hi(res_lo(a1.x), res_lo(a1.y));
                l.u.w = pack_hi(res_lo(a1.z), res_lo(a1.w));
                al[mi] = l.s;
            }
        }
        // ---- B fragments per ni + MFMA ----
        #pragma unroll
        for (int ni = 0; ni < 4; ni++) {
            const int g = wv * 64 + ni * 16 + l15;
            float w[8];
            #pragma unroll
            for (int j = 0; j < 8; j++) w[j] = Wf[(quad * 8 + j) * 256 + g];
            U4S8 bh;
            bh.u.x = pack_hi(w[0], w[1]); bh.u.y = pack_hi(w[2], w[3]);
            bh.u.z = pack_hi(w[4], w[5]); bh.u.w = pack_hi(w[6], w[7]);
            if (SPLIT) {
                U4S8 bl;
                bl.u.x = pack_hi(res_lo(w[0]), res_lo(w[1]));
                bl.u.y = pack_hi(res_lo(w[2]), res_lo(w[3]));
                bl.u.z = pack_hi(res_lo(w[4]), res_lo(w[5]));
                bl.u.w = pack_hi(res_lo(w[6]), res_lo(w[7]));
                #pragma unroll
                for (int mi = 0; mi < 4; mi++) {
                    acc[mi][ni] = __builtin_amdgcn_mfma_f32_16x16x32_bf16(al[mi], bh.s, acc[mi][ni], 0, 0, 0);
                    acc[mi][ni] = __builtin_amdgcn_mfma_f32_16x16x32_bf16(ah[mi], bl.s, acc[mi][ni], 0, 0, 0);
                    acc[mi][ni] = __builtin_amdgcn_mfma_f32_16x16x32_bf16(ah[mi], bh.s, acc[mi][ni], 0, 0, 0);
                }
            } else {
                #pragma unroll
                for (int mi = 0; mi < 4; mi++)
                    acc[mi][ni] = __builtin_amdgcn_mfma_f32_16x16x32_bf16(ah[mi], bh.s, acc[mi][ni], 0, 0, 0);
            }
        }
    }
}

// Kernel 1: qws[n][b][g] (fp32) = Q[b,n,:] @ Wq[n] + bq[n]
__global__ __launch_bounds__(256, 2) void k_qproj(
    const float* __restrict__ Q, const float* __restrict__ Wq,
    const float* __restrict__ bq, float* __restrict__ qws)
{
    const int n = blockIdx.x;
    __shared__ Smem sm;
    f32x4 acc[4][4];
    #pragma unroll
    for (int i = 0; i < 4; i++)
        #pragma unroll
        for (int j = 0; j < 4; j++) acc[i][j] = (f32x4){0.f, 0.f, 0.f, 0.f};

    gemm_f32<true>(Q + n * F_, (long)(N_ * F_), Wq + (long)n * F_ * F_, sm, acc);

    const int t = threadIdx.x, lane = t & 63, wv = t >> 6;
    const int l15 = lane & 15, quad = lane >> 4;
    const float* bias = bq + n * F_;
    float* dst = qws + (long)n * (B_ * F_);
    #pragma unroll
    for (int ni = 0; ni < 4; ni++) {
        int g = wv * 64 + ni * 16 + l15;
        float bb = bias[g];
        #pragma unroll
        for (int mi = 0; mi < 4; mi++)
            #pragma unroll
            for (int reg = 0; reg < 4; reg++) {
                int r = mi * 16 + quad * 4 + reg;
                dst[r * 256 + g] = acc[mi][ni][reg] + bb;
            }
    }
}

// Kernel 2: grid (N*H, 2). y==0: KWk (split) + fused logits. y==1: VWv -> vws bf16.
__global__ __launch_bounds__(256, 2) void k_kvproj(
    const float* __restrict__ Kx, const float* __restrict__ Vx,
    const float* __restrict__ Wk, const float* __restrict__ bk,
    const float* __restrict__ Wv, const float* __restrict__ bv,
    const float* __restrict__ qws, float* __restrict__ logits,
    unsigned short* __restrict__ vws)
{
    const int nh = blockIdx.x;
    const int n = nh / H_;
    const int h = nh - n * H_;
    const bool isV = (blockIdx.y != 0);
    const float* X    = isV ? Vx : Kx;
    const float* W    = (isV ? Wv : Wk) + (long)nh * F_ * F_;
    const float* bias = (isV ? bv : bk) + nh * F_;

    __shared__ Smem sm;
    const int t = threadIdx.x;

    f32x4 acc[4][4];
    #pragma unroll
    for (int i = 0; i < 4; i++)
        #pragma unroll
        for (int j = 0; j < 4; j++) acc[i][j] = (f32x4){0.f, 0.f, 0.f, 0.f};

    const float* Xb = X + (long)(h * N_ + n) * F_;
    if (isV) gemm_f32<false>(Xb, (long)(H_ * N_ * F_), W, sm, acc);
    else     gemm_f32<true >(Xb, (long)(H_ * N_ * F_), W, sm, acc);

    const int lane = t & 63, wv = t >> 6, l15 = lane & 15, quad = lane >> 4;

    if (!isV) {
        // slog aliases staging LDS: all frag reads are barrier-drained above
        __syncthreads();
        if (t < 64) sm.slog[t] = 0.f;
        __syncthreads();
        // logits[b] = sum_g qws[n,b,g] * (KWk[b,g] + bk[g])
        const float* qrow = qws + (long)n * (B_ * F_);
        #pragma unroll
        for (int mi = 0; mi < 4; mi++) {
            float p[4] = {0.f, 0.f, 0.f, 0.f};
            #pragma unroll
            for (int ni = 0; ni < 4; ni++) {
                int g = wv * 64 + ni * 16 + l15;
                float bb = bias[g];
                #pragma unroll
                for (int reg = 0; reg < 4; reg++) {
                    int r = mi * 16 + quad * 4 + reg;
                    p[reg] += (acc[mi][ni][reg] + bb) * qrow[r * 256 + g];
                }
            }
            #pragma unroll
            for (int off = 1; off < 16; off <<= 1)
                #pragma unroll
                for (int reg = 0; reg < 4; reg++)
                    p[reg] += __shfl_xor(p[reg], off, 64);
            if (l15 == 0)
                #pragma unroll
                for (int reg = 0; reg < 4; reg++)
                    atomicAdd(&sm.slog[mi * 16 + quad * 4 + reg], p[reg]);
        }
        __syncthreads();
        if (t < 64) logits[(long)nh * 64 + t] = sm.slog[t];
    } else {
        __syncthreads();   // frag reads done before overwriting smem
        #pragma unroll
        for (int ni = 0; ni < 4; ni++) {
            int g = wv * 64 + ni * 16 + l15;
            float bb = bias[g];
            #pragma unroll
            for (int mi = 0; mi < 4; mi++)
                #pragma unroll
                for (int reg = 0; reg < 4; reg++) {
                    int r = mi * 16 + quad * 4 + reg;
                    sm.outT[r * 256 + g] = f2bf(acc[mi][ni][reg] + bb);
                }
        }
        __syncthreads();
        unsigned short* dst = vws + (long)nh * (B_ * F_);
        #pragma unroll
        for (int it = 0; it < 8; it++) {
            int row = it * 8 + (t >> 5);
            int c = t & 31;
            uint4 v = *(const uint4*)(&sm.outT[row * 256 + c * 8]);
            *(uint4*)(dst + row * 256 + c * 8) = v;
        }
    }
}

// Kernel 3: per (b,n): softmax over H, write scores, combine VWv -> heads
__global__ __launch_bounds__(64) void k_attn(
    const float* __restrict__ logits,
    const unsigned short* __restrict__ vws,
    float* __restrict__ out)
{
    const int bx = blockIdx.x;
    const int b = bx >> 5;      // B=64
    const int n = bx & 31;      // N=32
    const int t = threadIdx.x;
    __shared__ float sl[24], se[24];
    if (t < 24) sl[t] = logits[(long)(n * H_ + t) * 64 + b];
    __syncthreads();
    float mx = -1e30f;
    #pragma unroll
    for (int h = 0; h < H_; h++) mx = fmaxf(mx, sl[h]);
    if (t < 24) se[t] = expf(sl[t] - mx);
    __syncthreads();
    float den = 0.f;
    #pragma unroll
    for (int h = 0; h < H_; h++) den += se[h];
    float inv = 1.0f / den;
    if (t < 24)
        out[(long)B_ * N_ * F_ + (long)(b * N_ + n) * H_ + t] = se[t] * inv;

    const int g0 = t * 4;
    float hv[4] = {0.f, 0.f, 0.f, 0.f};
    #pragma unroll
    for (int h = 0; h < H_; h++) {
        float s = se[h] * inv;
        const unsigned short* vp = vws + (((long)(n * H_ + h) * 64 + b) << 8) + g0;
        union { uint2 u; unsigned short e[4]; } vv;
        vv.u = *(const uint2*)vp;
        #pragma unroll
        for (int j = 0; j < 4; j++) hv[j] += s * bf2f(vv.e[j]);
    }
    float4 ov = make_float4(hv[0], hv[1], hv[2], hv[3]);
    *(float4*)(out + ((long)b * N_ + n) * F_ + g0) = ov;
}

extern "C" void kernel_launch(void* const* d_in, const int* in_sizes, int n_in,
                              void* d_out, int out_size, void* d_ws, size_t ws_size,
                              hipStream_t stream) {
    const float* Q  = (const float*)d_in[0];
    const float* K  = (const float*)d_in[1];
    const float* V  = (const float*)d_in[2];
    const float* Wq = (const float*)d_in[3];
    const float* bq = (const float*)d_in[4];
    const float* Wk = (const float*)d_in[5];
    const float* bk = (const float*)d_in[6];
    const float* Wv = (const float*)d_in[7];
    const float* bv = (const float*)d_in[8];

    char* ws = (char*)d_ws;
    float* qws          = (float*)ws;                               // N*B*F fp32 = 2 MB
    float* logits       = (float*)(ws + 2097152);                   // N*H*B fp32 = 192 KB
    unsigned short* vws = (unsigned short*)(ws + 2097152 + 262144); // N*H*B*F bf16 = 24 MB

    k_qproj<<<N_, 256, 0, stream>>>(Q, Wq, bq, qws);
    k_kvproj<<<dim3(N_ * H_, 2), 256, 0, stream>>>(K, V, Wk, bk, Wv, bv, qws, logits, vws);
    k_attn<<<B_ * N_, 64, 0, stream>>>(logits, vws, (float*)d_out);
}